// Round 2
// baseline (162.637 us; speedup 1.0000x reference)
//
#include <hip/hip_runtime.h>
#include <hip/hip_bf16.h>

// AAConv2d: B=8, CIN=128, H=W=32, COUT=128, K=3, DK=DV=64, NH=8, dkh=dvh=8
// out[:, 0:64]  = conv3x3(x, w_general) + b_general
// out[:, 64:128]= conv3x3(attn_combined, w_out) + b_out
// Rel logits (verified): logits[n,m] += dot(q[:, m>>5, n>>5], krw[(m&31)-(m>>5)+31])
//                                    + dot(q[:, m>>5, n>>5], krh[(n&31)-(n>>5)+31])
// flat_q/flat_k/flat_v are RAW reshapes: row n = linear elements n*8..n*8+7 of
// the channel-major (8,1024) head block.
// R15: P no longer round-trips through LDS. Key identity: the S-MFMA
// (16x16x32) C-layout gives lane (q,n) the values w[n][m=4q+r], which IS the
// A-fragment layout of a K=16 MFMA (16x16x16: A[row=lane&15][k=(lane>>4)*4+j]).
// PV = 2x mfma_f32_16x16x16_bf16 per 32-m chunk, P packed in-register.
// m-loop is now store-free (pipelines freely). Ak quad-zeroing cndmasks
// removed (Bq already zero on quads 1-3). vtb rows 8-15 left unzeroed
// (only feed discarded nIdx>=8 lanes). LDS 30.2->24.8 KB (6 blocks/CU).

#define NP 1024
#define QSCALE 2.8284271247461903f   // q / (8^-0.5) = q*sqrt(8)
#define LOG2E  1.4426950408889634f

using bf16 = __hip_bfloat16;
typedef unsigned short ushort;
typedef unsigned int uint;
using bf16x8 = __attribute__((ext_vector_type(8))) short;  // 8 bf16 = 4 VGPRs
using bf16x4 = __attribute__((ext_vector_type(4))) short;  // 4 bf16 = 2 VGPRs
using f32x4  = __attribute__((ext_vector_type(4))) float;
using f32x2  = __attribute__((ext_vector_type(2))) float;

__device__ __forceinline__ float b2f(bf16 v) { return __bfloat162float(v); }
__device__ __forceinline__ ushort f2b(float v) {
  bf16 h = __float2bfloat16(v);
  ushort u; __builtin_memcpy(&u, &h, 2); return u;
}
__device__ __forceinline__ f32x2 up2(uint u) {   // 2 packed bf16 -> 2 f32
  f32x2 r;
  r[0] = __uint_as_float(u << 16);
  r[1] = __uint_as_float(u & 0xffff0000u);
  return r;
}

__device__ __forceinline__ float dot8(const float* a, const float* b) {
  float s = a[0] * b[0];
  s = fmaf(a[1], b[1], s); s = fmaf(a[2], b[2], s); s = fmaf(a[3], b[3], s);
  s = fmaf(a[4], b[4], s); s = fmaf(a[5], b[5], s); s = fmaf(a[6], b[6], s);
  s = fmaf(a[7], b[7], s);
  return s;
}

__device__ __forceinline__ int fenc(float f) { int i = __float_as_int(f); return i < 0 ? (i ^ 0x7fffffff) : i; }
__device__ __forceinline__ float fdec(int i) { return __int_as_float(i < 0 ? (i ^ 0x7fffffff) : i); }

#if defined(__has_builtin)
#if __has_builtin(__builtin_amdgcn_exp2f)
#define EXP2F __builtin_amdgcn_exp2f
#else
#define EXP2F exp2f
#endif
#else
#define EXP2F exp2f
#endif

// K=16 bf16 MFMA (legacy shape, still on gfx950 per ISA §10). Builtin name
// varies across ROCm: try both spellings, else inline asm.
#if defined(__has_builtin)
#if __has_builtin(__builtin_amdgcn_mfma_f32_16x16x16_bf16)
#define MFMA16(A,B,C) __builtin_amdgcn_mfma_f32_16x16x16_bf16(A,B,C,0,0,0)
#elif __has_builtin(__builtin_amdgcn_mfma_f32_16x16x16bf16_1k)
#define MFMA16(A,B,C) __builtin_amdgcn_mfma_f32_16x16x16bf16_1k(A,B,C,0,0,0)
#endif
#endif
#ifndef MFMA16
__device__ __forceinline__ f32x4 mfma16_asm(bf16x4 a, bf16x4 b, f32x4 c) {
  f32x4 d;
  asm volatile("v_mfma_f32_16x16x16_bf16 %0, %1, %2, %3"
               : "=v"(d) : "v"(a), "v"(b), "v"(c));
  return d;
}
#define MFMA16(A,B,C) mfma16_asm(A,B,C)
#endif

// ---- workspace float offsets ----------------------------------------------
#define OFF_QBUF   0          // f32 [8][64][1024]
#define OFF_KB16   524288     // ushort[8][64][1024] raw channel-major bf16
#define OFF_VTB    786432     // ushort[64 heads][16][1024] V^T (rows 8-15 garbage, unused)
#define OFF_XPB    1310720    // ushort[8][34][34][128]
#define OFF_APB    1902592    // ushort[8][34][34][64]
#define OFF_WGB    2198528    // ushort[9][64][128]
#define OFF_WOB    2235392    // ushort[9][64][64]
#define OFF_BG     2253824
#define OFF_BQKV   2253888
#define OFF_BO     2254080
#define OFF_KRH    2254144
#define OFF_KRW    2254648
#define OFF_FLAG   2255152
#define OFF_WQB    2255168    // ushort[192][128] bf16 w_qkv (16B-aligned)

// ---------------------------------------------------------------------------
// Kernel 0: dtype detect + small fp32 copies + halo zeroing +
// weight bf16 transforms (wgb, wob, wqb) + (blocks<128) x->xpb bf16 transpose.
// ---------------------------------------------------------------------------
__global__ __launch_bounds__(256) void cvt_kernel(
    const void* __restrict__ p0, const void* __restrict__ p1, const void* __restrict__ p2,
    const void* __restrict__ p3, const void* __restrict__ p4, const void* __restrict__ p5,
    const void* __restrict__ p6, const void* __restrict__ p7, const void* __restrict__ p8,
    float* __restrict__ ws, int* __restrict__ flag)
{
  __shared__ int partial[4];
  __shared__ uint lds[64][65];
  int t = threadIdx.x;
  const unsigned* xraw = (const unsigned*)p0;
  int cnt = 0;
  for (int i = t; i < 1024; i += 256) {
    unsigned elo = (xraw[i] >> 7) & 0xffu;
    cnt += (elo >= 64u && elo <= 133u) ? 1 : 0;
  }
#pragma unroll
  for (int off = 1; off < 64; off <<= 1) cnt += __shfl_xor(cnt, off);
  if ((t & 63) == 0) partial[t >> 6] = cnt;
  __syncthreads();
  int tot = partial[0] + partial[1] + partial[2] + partial[3];
  int f32 = (tot >= 650) ? 0 : 1;   // 1 = fp32 tensors, 0 = bf16 tensors
  if (blockIdx.x == 0 && t == 0) *flag = f32;

  int gsz = gridDim.x * 256;
  int gid = blockIdx.x * 256 + t;

  // small fp32 copies (bg, bqkv, bo, krh, krw)
  const void* src[5] = {p2, p4, p6, p7, p8};
  const int   n[5]    = {64, 192, 64, 504, 504};
  const int   doff[5] = {OFF_BG, OFF_BQKV, OFF_BO, OFF_KRH, OFF_KRW};
#pragma unroll
  for (int s = 0; s < 5; s++) {
    float* dst = ws + doff[s];
    if (f32) { const float* sp = (const float*)src[s];
      for (int i = gid; i < n[s]; i += gsz) dst[i] = sp[i];
    } else { const bf16* sp = (const bf16*)src[s];
      for (int i = gid; i < n[s]; i += gsz) dst[i] = b2f(sp[i]);
    }
  }

  // halo zeroing: xpb (16 uint4/px), apb (8 uint4/px)
  {
    uint4 z = {0u, 0u, 0u, 0u};
    uint4* xp = (uint4*)(ws + OFF_XPB);
    uint4* ap = (uint4*)(ws + OFF_APB);
    for (int s = gid; s < 9248; s += gsz) {
      int pb = s / 1156, rem = s - pb * 1156;
      int y = rem / 34, x = rem - y * 34;
      if (y == 0 || y == 33 || x == 0 || x == 33) {
        uint4* d1 = xp + (size_t)s * 16;
#pragma unroll
        for (int k = 0; k < 16; k++) d1[k] = z;
        uint4* d2 = ap + (size_t)s * 8;
#pragma unroll
        for (int k = 0; k < 8; k++) d2[k] = z;
      }
    }
  }

  // w_general -> wgb bf16 [kykx][co][ci]
  {
    ushort* wgb = (ushort*)(ws + OFF_WGB);
    for (int s = gid; s < 73728; s += gsz) {
      int kykx = s >> 13, co = (s >> 7) & 63, ci = s & 127;
      int si = (co * 128 + ci) * 9 + kykx;
      wgb[s] = f32 ? f2b(((const float*)p1)[si]) : ((const ushort*)p1)[si];
    }
  }
  // w_out -> wob bf16 [kykx][co][ci]
  {
    ushort* wob = (ushort*)(ws + OFF_WOB);
    for (int s = gid; s < 36864; s += gsz) {
      int kykx = s >> 12, co = (s >> 6) & 63, ci = s & 63;
      int si = (co * 64 + ci) * 9 + kykx;
      wob[s] = f32 ? f2b(((const float*)p5)[si]) : ((const ushort*)p5)[si];
    }
  }
  // w_qkv -> wqb bf16 [co][ci] (already [192][128] contiguous)
  {
    ushort* wqb = (ushort*)(ws + OFF_WQB);
    for (int s = gid; s < 24576; s += gsz) {
      wqb[s] = f32 ? f2b(((const float*)p3)[s]) : ((const ushort*)p3)[s];
    }
  }

  // x -> xpb interior transpose (blocks 0..127): 64 px x 128 ci per block
  if (blockIdx.x < 128) {
    int w = t >> 6, lane = t & 63;
    int b = blockIdx.x >> 4;
    int pp0 = (blockIdx.x & 15) * 64;
    if (f32) {
      const float* xs = (const float*)p0 + (size_t)b * 131072 + pp0;
#pragma unroll 4
      for (int i = 0; i < 16; i++) {
        int cp = w * 16 + i;
        float v0 = xs[(size_t)(2 * cp) * 1024 + lane];
        float v1 = xs[(size_t)(2 * cp + 1) * 1024 + lane];
        lds[cp][lane] = (uint)f2b(v0) | ((uint)f2b(v1) << 16);
      }
    } else {
      const ushort* xs = (const ushort*)p0 + (size_t)b * 131072 + pp0;
#pragma unroll 4
      for (int i = 0; i < 16; i++) {
        int cp = w * 16 + i;
        uint v0 = xs[(size_t)(2 * cp) * 1024 + lane];
        uint v1 = xs[(size_t)(2 * cp + 1) * 1024 + lane];
        lds[cp][lane] = v0 | (v1 << 16);
      }
    }
    __syncthreads();
    uint* xp32 = (uint*)(ws + OFF_XPB);
#pragma unroll 4
    for (int i = 0; i < 16; i++) {
      int p = w * 16 + i;
      int pp = pp0 + p;
      int y = pp >> 5, x = pp & 31;
      xp32[((size_t)(b * 34 + y + 1) * 34 + x + 1) * 64 + lane] = lds[lane][p];
    }
  }
}

// ---------------------------------------------------------------------------
// Kernel 1: qkv 1x1 conv as bf16 MFMA implicit GEMM on xpb center taps.
// grid (pxtile=64, b=8) = 512 blocks, 4 waves. Wave w covers co-groups
// {w, w+4, w+8} (q co 0..63, k co 64..127, v co 128..191).
// ---------------------------------------------------------------------------
__global__ __launch_bounds__(256) void qkv_mfma_kernel(
    const ushort* __restrict__ xp, const ushort* __restrict__ wqb,
    const float* __restrict__ bias, float* __restrict__ qbuf,
    ushort* __restrict__ kb16, ushort* __restrict__ vtb)
{
  int pt = blockIdx.x;            // px tile: 16 px
  int b  = blockIdx.y;
  int lane = threadIdx.x & 63;
  int w = threadIdx.x >> 6;       // wave 0..3
  int n = lane & 15;              // shared m/n index
  int kg = lane >> 4;             // k-group (8 ci each)
  int p0 = pt * 16;
  int px = p0 + n;
  int y = px >> 5, x = px & 31;

  const ushort* bbase = xp + ((size_t)(b * 34 + y + 1) * 34 + (x + 1)) * 128 + kg * 8;
  bf16x8 Bf[4];
#pragma unroll
  for (int c = 0; c < 4; c++) Bf[c] = *(const bf16x8*)(bbase + c * 32);

  f32x4 acc0 = {0.f, 0.f, 0.f, 0.f};
  f32x4 acc1 = {0.f, 0.f, 0.f, 0.f};
  f32x4 acc2 = {0.f, 0.f, 0.f, 0.f};
  {
    const ushort* abase = wqb + (size_t)(w * 16 + n) * 128 + kg * 8;
#pragma unroll
    for (int c = 0; c < 4; c++) {
      bf16x8 A = *(const bf16x8*)(abase + c * 32);
      acc0 = __builtin_amdgcn_mfma_f32_16x16x32_bf16(A, Bf[c], acc0, 0, 0, 0);
    }
  }
  {
    const ushort* abase = wqb + (size_t)((w + 4) * 16 + n) * 128 + kg * 8;
#pragma unroll
    for (int c = 0; c < 4; c++) {
      bf16x8 A = *(const bf16x8*)(abase + c * 32);
      acc1 = __builtin_amdgcn_mfma_f32_16x16x32_bf16(A, Bf[c], acc1, 0, 0, 0);
    }
  }
  {
    const ushort* abase = wqb + (size_t)((w + 8) * 16 + n) * 128 + kg * 8;
#pragma unroll
    for (int c = 0; c < 4; c++) {
      bf16x8 A = *(const bf16x8*)(abase + c * 32);
      acc2 = __builtin_amdgcn_mfma_f32_16x16x32_bf16(A, Bf[c], acc2, 0, 0, 0);
    }
  }

  // epilogue: D row = kg*4+r (co within group), D col = n (px)
#pragma unroll
  for (int r = 0; r < 4; r++) {
    int co = w * 16 + kg * 4 + r;             // 0..63
    float v = acc0[r] + bias[co];
    qbuf[((size_t)b * 64 + co) * NP + px] = v * QSCALE;
  }
#pragma unroll
  for (int r = 0; r < 4; r++) {
    int co = (w + 4) * 16 + kg * 4 + r;       // 64..127
    float v = acc1[r] + bias[co];
    kb16[((size_t)b * 64 + (co - 64)) * NP + px] = f2b(v);
  }
#pragma unroll
  for (int r = 0; r < 4; r++) {
    int co = (w + 8) * 16 + kg * 4 + r;       // 128..191
    float v = acc2[r] + bias[co];
    int ch = co - 128;
    int h = ch >> 3;
    int d0 = px & 7;
    int m  = (ch & 7) * 128 + (px >> 3);
    vtb[((size_t)(b * 8 + h) * 16 + d0) * 1024 + m] = f2b(v);
  }
}

// ---------------------------------------------------------------------------
// conv3x3 body as bf16 MFMA implicit GEMM; dual acc chains.
// ---------------------------------------------------------------------------
template <int CINT>
__device__ __forceinline__ void conv_body(
    const ushort* __restrict__ xp, const ushort* __restrict__ wp,
    const float* __restrict__ bias, void* __restrict__ out,
    int co_base, const int* __restrict__ flag, int pt, int b)
{
  int lane = threadIdx.x & 63;
  int w = threadIdx.x >> 6;       // wave -> co group (16 co)
  int n = lane & 15;              // A: m (co); B: n (px); shared index
  int kg = lane >> 4;             // k-group (8 ci each)
  int p0 = pt * 16;
  int y = p0 >> 5, x0 = p0 & 31;

  const ushort* abase = wp + (size_t)(w * 16 + n) * CINT + kg * 8;
  const ushort* bbase = xp + ((size_t)(b * 34 + y) * 34 + x0 + n) * CINT + kg * 8;

  f32x4 acc0 = {0.f, 0.f, 0.f, 0.f};
  f32x4 acc1 = {0.f, 0.f, 0.f, 0.f};
#pragma unroll
  for (int c = 0; c < CINT / 32; c++) {
    int ci0 = c * 32;
#pragma unroll
    for (int kp = 0; kp < 9; kp++) {
      int ky = kp / 3, kx = kp - ky * 3;
      bf16x8 A = *(const bf16x8*)(abase + (size_t)kp * 64 * CINT + ci0);
      bf16x8 B = *(const bf16x8*)(bbase + (size_t)(ky * 34 + kx) * CINT + ci0);
      if (kp & 1) acc1 = __builtin_amdgcn_mfma_f32_16x16x32_bf16(A, B, acc1, 0, 0, 0);
      else        acc0 = __builtin_amdgcn_mfma_f32_16x16x32_bf16(A, B, acc0, 0, 0, 0);
    }
  }

  int f32o = *flag;
#pragma unroll
  for (int r = 0; r < 4; r++) {
    int co = w * 16 + kg * 4 + r;        // D row = (lane>>4)*4 + r
    float v = acc0[r] + acc1[r] + bias[co];
    size_t eoff = ((size_t)b * 128 + co_base + co) * 1024 + p0 + n;   // D col = n
    if (f32o) ((float*)out)[eoff] = v;
    else ((bf16*)out)[eoff] = __float2bfloat16(v);
  }
}

// ---------------------------------------------------------------------------
// Kernel 2: MERGED: blocks 0..1023 = MFMA flash attention; blocks 1024..1535 =
// conv3x3 co 0..63 (independent; backfills CUs).
// Attention m-loop per 32-chunk: 2 S-MFMAs (16x16x32, d=8 in quad0 of K) ->
// exp chain -> in-register bf16 pack -> 2 PV-MFMAs (16x16x16). Store-free.
// ---------------------------------------------------------------------------
__global__ __launch_bounds__(256, 4) void attn_conv_kernel(
    const float* __restrict__ qbuf, const ushort* __restrict__ kb16, const ushort* __restrict__ vtb,
    const float* __restrict__ krh, const float* __restrict__ krw,
    ushort* __restrict__ apb,
    const ushort* __restrict__ xp, const ushort* __restrict__ wgb,
    const float* __restrict__ bg, void* __restrict__ out, const int* __restrict__ flag)
{
  int bx = blockIdx.x;
  if (bx >= 1024) {
    int id = bx - 1024;
    conv_body<128>(xp, wgb, bg, out, 0, flag, id & 63, id >> 6);
    return;
  }

  __shared__ float bw2[2][NP];        // 8 KB (scaled by log2e)
  __shared__ float bhT[2][32][32];    // 8 KB (scaled by log2e)
  __shared__ float qsT[2][32][8];     // 2 KB
  __shared__ __align__(16) float krhs[64][12];  // 48B rows: 16B-aligned
  __shared__ __align__(16) float krws[64][12];
  __shared__ float lred[4][16];
  __shared__ int smax[3];

  int t = threadIdx.x;
  int cp = bx & 15, h = (bx >> 4) & 7, b = bx >> 7;
  int C0 = cp * 2;
  const float* qbase = qbuf + ((size_t)b * 64 + h * 8) * NP;
  const uint4* kb4 = (const uint4*)(kb16 + ((size_t)b * 64 + h * 8) * NP);
  const ushort* vth = vtb + (size_t)(b * 8 + h) * 16384;

  if (t < 3) smax[t] = (t == 0) ? 0 : fenc(-3.0e38f);

  for (int idx = t; idx < 63 * 8; idx += 256) {
    krhs[idx >> 3][idx & 7] = krh[idx];
    krws[idx >> 3][idx & 7] = krw[idx];
  }
  {
    int d = t >> 5, r = t & 31;      // 256 threads cover [8][32]
    float2 qv = *(const float2*)(qbase + (size_t)d * NP + r * 32 + C0);
    qsT[0][r][d] = qv.x;
    qsT[1][r][d] = qv.y;
  }
  // scan bf16 flat_k rows for max ||k_m||^2 (same data the MFMA consumes)
  float kn2 = 0.f;
#pragma unroll
  for (int rr = 0; rr < 4; rr++) {
    uint4 ku = kb4[rr * 256 + t];
    f32x2 k0 = up2(ku.x), k1 = up2(ku.y), k2 = up2(ku.z), k3 = up2(ku.w);
    f32x2 s2 = k0 * k0;
    s2 = __builtin_elementwise_fma(k1, k1, s2);
    s2 = __builtin_elementwise_fma(k2, k2, s2);
    s2 = __builtin_elementwise_fma(k3, k3, s2);
    kn2 = fmaxf(kn2, s2[0] + s2[1]);
  }
  __syncthreads();
  atomicMax(&smax[0], __float_as_int(kn2));

  float bwm = -3.0e38f;
  for (int idx = t; idx < 2048; idx += 256) {
    int cs = idx >> 10, m = idx & 1023;
    int rg = m >> 5, j2 = m & 31;
    float s = dot8(qsT[cs][rg], krws[j2 - rg + 31]) * LOG2E;
    bw2[cs][m] = s;
    bwm = fmaxf(bwm, s);
  }
  float bhm = -3.0e38f;
  for (int idx = t; idx < 2048; idx += 256) {
    int cs = idx >> 10, r = idx & 1023;
    int i = r >> 5, J = r & 31;
    float s = dot8(qsT[cs][i], krhs[J - (C0 + cs) + 31]) * LOG2E;
    bhT[cs][i][J] = s;
    bhm = fmaxf(bhm, s);
  }
  atomicMax(&smax[1], fenc(bwm));
  atomicMax(&smax[2], fenc(bhm));
  __syncthreads();

  float kmaxn = sqrtf(__int_as_float(smax[0]));
  float bmax = fdec(smax[1]) + fdec(smax[2]);

  int w = t >> 6, lane = t & 63;
  int quad = lane >> 4, nIdx = lane & 15;
  int n0 = cp * 64 + w * 16;
  int nQ = n0 + nIdx;
  int Cs = w >> 1;
  int J = ((w & 1) << 4) + nIdx;       // n & 31 for this lane's column

  const bf16x8 zero8 = {0, 0, 0, 0, 0, 0, 0, 0};

  // Q B-frag (bf16): quad 0 holds the 8 real d values, others zero.
  // Mn = ||q~|| * kmax + bmax using the bf16-rounded q (exact upper bound).
  const float* qrow = qbase + (size_t)nQ * 8;
  bf16x8 Bq = zero8;
  float nn = 0.f;
  ushort ub[8];
#pragma unroll
  for (int d = 0; d < 8; d++) {
    float v = qrow[d] * LOG2E;
    ub[d] = f2b(v);
    float vr = __uint_as_float((uint)ub[d] << 16);
    nn = fmaf(vr, vr, nn);
  }
  if (quad == 0) {
#pragma unroll
    for (int d = 0; d < 8; d++) Bq[d] = (short)ub[d];
  }
  float Mn = sqrtf(nn) * kmaxn + bmax;

  f32x4 accO = {0.f, 0.f, 0.f, 0.f};
  float lpart = 0.f;
  const uint4* krow = kb4 + nIdx;                             // rows m = mt+nIdx
  const ushort* vrow = vth + (size_t)nIdx * 1024 + (quad << 2); // V^T row d=nIdx

#pragma unroll 2
  for (int mc = 0; mc < 32; ++mc) {
    int mb = mc * 32;
    float pre = bhT[Cs][mc][J] - Mn;
    // global loads (store-free loop: scheduler pipelines these across iters)
    bf16x8 a0 = *(const bf16x8*)(krow + mb);         // K rows mb+nIdx, d0..7
    bf16x8 a1 = *(const bf16x8*)(krow + mb + 16);
    uint2 v0u = *(const uint2*)(vrow + mb);          // V^T[nIdx][mb+4q .. +3]
    uint2 v1u = *(const uint2*)(vrow + mb + 16);
    // S tiles: quads 1-3 of A are garbage but B (Bq) is zero there.
    f32x4 S0 = __builtin_amdgcn_mfma_f32_16x16x32_bf16(a0, Bq, f32x4{0.f,0.f,0.f,0.f}, 0, 0, 0);
    f32x4 S1 = __builtin_amdgcn_mfma_f32_16x16x32_bf16(a1, Bq, f32x4{0.f,0.f,0.f,0.f}, 0, 0, 0);
    float4 bwA = *(const float4*)&bw2[Cs][mb + (quad << 2)];
    float4 bwB = *(const float4*)&bw2[Cs][mb + 16 + (quad << 2)];
    float p0 = EXP2F(S0[0] + bwA.x + pre);
    float p1 = EXP2F(S0[1] + bwA.y + pre);
    float p2 = EXP2F(S0[2] + bwA.z + pre);
    float p3 = EXP2F(S0[3] + bwA.w + pre);
    float p4 = EXP2F(S1[0] + bwB.x + pre);
    float p5 = EXP2F(S1[1] + bwB.y + pre);
    float p6 = EXP2F(S1[2] + bwB.z + pre);
    float p7 = EXP2F(S1[3] + bwB.w + pre);
    lpart += ((p0 + p1) + (p2 + p3)) + ((p4 + p5) + (p6 + p7));
    // C-layout (w[n=nIdx][m=4q+r]) IS the K=16 A-frag layout: pack in-register.
    uint2 ua, ub2;
    ua.x  = (uint)f2b(p0) | ((uint)f2b(p1) << 16);
    ua.y  = (uint)f2b(p2) | ((uint)f2b(p3) << 16);
    ub2.x = (uint)f2b(p4) | ((uint)f2b(p5) << 16);
    ub2.y = (uint)f2b(p6) | ((uint)f2b(p7) << 16);
    accO = MFMA16(__builtin_bit_cast(bf16x4, ua),  __builtin_bit_cast(bf16x4, v0u), accO);
    accO = MFMA16(__builtin_bit_cast(bf16x4, ub2), __builtin_bit_cast(bf16x4, v1u), accO);
  }

  // l: lane has partial for col nIdx over its rows; reduce across quads
  lpart += __shfl_xor(lpart, 16);
  lpart += __shfl_xor(lpart, 32);
  if (lane < 16) lred[w][lane] = lpart;
  float4 lr4 = *(const float4*)&lred[w][quad << 2];
  const float lr[4] = {lr4.x, lr4.y, lr4.z, lr4.w};

  // O: lane holds O[n = n0+quad*4+r][d = nIdx] (d >= 8 lanes discard)
  if (nIdx < 8) {
#pragma unroll
    for (int r = 0; r < 4; ++r) {
      int n = n0 + (quad << 2) + r;
      float v = accO[r] / lr[r];
      apb[((size_t)(b * 34 + (n >> 5) + 1) * 34 + (n & 31) + 1) * 64 + h * 8 + nIdx] = f2b(v);
    }
  }
}

// ---------------------------------------------------------------------------
// Kernel 3: standalone conv3x3 (co 64..127, reads apb).
// ---------------------------------------------------------------------------
template <int CINT>
__global__ __launch_bounds__(256) void conv_mfma_kernel(
    const ushort* __restrict__ xp, const ushort* __restrict__ wp,
    const float* __restrict__ bias, void* __restrict__ out,
    int co_base, const int* __restrict__ flag)
{
  conv_body<CINT>(xp, wp, bias, out, co_base, flag, blockIdx.x, blockIdx.y);
}

// ---------------------------------------------------------------------------
extern "C" void kernel_launch(void* const* d_in, const int* in_sizes, int n_in,
                              void* d_out, int out_size, void* d_ws, size_t ws_size,
                              hipStream_t stream) {
  float* ws = (float*)d_ws;
  float*  qbuf  = ws + OFF_QBUF;
  ushort* kb16  = (ushort*)(ws + OFF_KB16);
  ushort* vtb   = (ushort*)(ws + OFF_VTB);
  ushort* xpb   = (ushort*)(ws + OFF_XPB);
  ushort* apb   = (ushort*)(ws + OFF_APB);
  ushort* wgb   = (ushort*)(ws + OFF_WGB);
  ushort* wob   = (ushort*)(ws + OFF_WOB);
  ushort* wqb   = (ushort*)(ws + OFF_WQB);
  float*  bgf   = ws + OFF_BG;
  float*  bqkvf = ws + OFF_BQKV;
  float*  bof   = ws + OFF_BO;
  float*  krhf  = ws + OFF_KRH;
  float*  krwf  = ws + OFF_KRW;
  int*    flag  = (int*)(ws + OFF_FLAG);

  cvt_kernel<<<512, 256, 0, stream>>>(d_in[0], d_in[1], d_in[2], d_in[3], d_in[4],
                                      d_in[5], d_in[6], d_in[7], d_in[8], ws, flag);
  qkv_mfma_kernel<<<dim3(64, 8), 256, 0, stream>>>(xpb, wqb, bqkvf, qbuf, kb16, vtb);
  attn_conv_kernel<<<1536, 256, 0, stream>>>(qbuf, kb16, vtb, krhf, krwf, apb,
                                             xpb, wgb, bgf, d_out, flag);
  conv_mfma_kernel<64><<<dim3(64, 8), 256, 0, stream>>>(apb, wob, bof, d_out, 64, flag);
}

// Round 3
// 149.658 us; speedup vs baseline: 1.0867x; 1.0867x over previous
//
#include <hip/hip_runtime.h>
#include <hip/hip_bf16.h>

// AAConv2d: B=8, CIN=128, H=W=32, COUT=128, K=3, DK=DV=64, NH=8, dkh=dvh=8
// out[:, 0:64]  = conv3x3(x, w_general) + b_general
// out[:, 64:128]= conv3x3(attn_combined, w_out) + b_out
// Rel logits (verified): logits[n,m] += dot(q[:, m>>5, n>>5], krw[(m&31)-(m>>5)+31])
//                                    + dot(q[:, m>>5, n>>5], krh[(n&31)-(n>>5)+31])
// flat_q/flat_k/flat_v are RAW reshapes: row n = linear elements n*8..n*8+7 of
// the channel-major (8,1024) head block.
// R16: revert PV to the proven R14 Plds round-trip + 16x16x32 MFMA (R15's
// in-register K=16 PV regressed 49->70us). Keep R15 cleanups (no A-cndmask,
// vectorized qsT fill, no vtb zero-fill). New: (a) LDS diet via qsT/Plds
// union + unpadded kr rows -> 25.6KB -> 6 blocks/CU -> all 1536 blocks
// co-resident (kills the 256-block second-round tail of R14's 5/CU); (b) V^T
// row d=8 = 1.0 so the PV MFMA's wasted col 8 accumulates l = sum_m P[n][m]
// for free (drops lpart adds + shfl reduce + lred).

#define NP 1024
#define QSCALE 2.8284271247461903f   // q / (8^-0.5) = q*sqrt(8)
#define LOG2E  1.4426950408889634f

using bf16 = __hip_bfloat16;
typedef unsigned short ushort;
typedef unsigned int uint;
using bf16x8 = __attribute__((ext_vector_type(8))) short;  // 8 bf16 = 4 VGPRs
using f32x4  = __attribute__((ext_vector_type(4))) float;
using f32x2  = __attribute__((ext_vector_type(2))) float;

__device__ __forceinline__ float b2f(bf16 v) { return __bfloat162float(v); }
__device__ __forceinline__ ushort f2b(float v) {
  bf16 h = __float2bfloat16(v);
  ushort u; __builtin_memcpy(&u, &h, 2); return u;
}
__device__ __forceinline__ f32x2 up2(uint u) {   // 2 packed bf16 -> 2 f32
  f32x2 r;
  r[0] = __uint_as_float(u << 16);
  r[1] = __uint_as_float(u & 0xffff0000u);
  return r;
}

__device__ __forceinline__ float dot8(const float* a, const float* b) {
  float s = a[0] * b[0];
  s = fmaf(a[1], b[1], s); s = fmaf(a[2], b[2], s); s = fmaf(a[3], b[3], s);
  s = fmaf(a[4], b[4], s); s = fmaf(a[5], b[5], s); s = fmaf(a[6], b[6], s);
  s = fmaf(a[7], b[7], s);
  return s;
}

__device__ __forceinline__ int fenc(float f) { int i = __float_as_int(f); return i < 0 ? (i ^ 0x7fffffff) : i; }
__device__ __forceinline__ float fdec(int i) { return __int_as_float(i < 0 ? (i ^ 0x7fffffff) : i); }

#if defined(__has_builtin)
#if __has_builtin(__builtin_amdgcn_exp2f)
#define EXP2F __builtin_amdgcn_exp2f
#else
#define EXP2F exp2f
#endif
#else
#define EXP2F exp2f
#endif

// ---- workspace float offsets ----------------------------------------------
#define OFF_QBUF   0          // f32 [8][64][1024]
#define OFF_KB16   524288     // ushort[8][64][1024] raw channel-major bf16
#define OFF_VTB    786432     // ushort[64 heads][16][1024] V^T (row 8 = ones; 9-15 garbage)
#define OFF_XPB    1310720    // ushort[8][34][34][128]
#define OFF_APB    1902592    // ushort[8][34][34][64]
#define OFF_WGB    2198528    // ushort[9][64][128]
#define OFF_WOB    2235392    // ushort[9][64][64]
#define OFF_BG     2253824
#define OFF_BQKV   2253888
#define OFF_BO     2254080
#define OFF_KRH    2254144
#define OFF_KRW    2254648
#define OFF_FLAG   2255152
#define OFF_WQB    2255168    // ushort[192][128] bf16 w_qkv (16B-aligned)

// ---------------------------------------------------------------------------
// Kernel 0: dtype detect + small fp32 copies + halo zeroing + V^T ones-row +
// weight bf16 transforms (wgb, wob, wqb) + (blocks<128) x->xpb bf16 transpose.
// ---------------------------------------------------------------------------
__global__ __launch_bounds__(256) void cvt_kernel(
    const void* __restrict__ p0, const void* __restrict__ p1, const void* __restrict__ p2,
    const void* __restrict__ p3, const void* __restrict__ p4, const void* __restrict__ p5,
    const void* __restrict__ p6, const void* __restrict__ p7, const void* __restrict__ p8,
    float* __restrict__ ws, int* __restrict__ flag)
{
  __shared__ int partial[4];
  __shared__ uint lds[64][65];
  int t = threadIdx.x;
  const unsigned* xraw = (const unsigned*)p0;
  int cnt = 0;
  for (int i = t; i < 1024; i += 256) {
    unsigned elo = (xraw[i] >> 7) & 0xffu;
    cnt += (elo >= 64u && elo <= 133u) ? 1 : 0;
  }
#pragma unroll
  for (int off = 1; off < 64; off <<= 1) cnt += __shfl_xor(cnt, off);
  if ((t & 63) == 0) partial[t >> 6] = cnt;
  __syncthreads();
  int tot = partial[0] + partial[1] + partial[2] + partial[3];
  int f32 = (tot >= 650) ? 0 : 1;   // 1 = fp32 tensors, 0 = bf16 tensors
  if (blockIdx.x == 0 && t == 0) *flag = f32;

  int gsz = gridDim.x * 256;
  int gid = blockIdx.x * 256 + t;

  // small fp32 copies (bg, bqkv, bo, krh, krw)
  const void* src[5] = {p2, p4, p6, p7, p8};
  const int   n[5]    = {64, 192, 64, 504, 504};
  const int   doff[5] = {OFF_BG, OFF_BQKV, OFF_BO, OFF_KRH, OFF_KRW};
#pragma unroll
  for (int s = 0; s < 5; s++) {
    float* dst = ws + doff[s];
    if (f32) { const float* sp = (const float*)src[s];
      for (int i = gid; i < n[s]; i += gsz) dst[i] = sp[i];
    } else { const bf16* sp = (const bf16*)src[s];
      for (int i = gid; i < n[s]; i += gsz) dst[i] = b2f(sp[i]);
    }
  }

  // V^T row d=8 := 1.0 (bf16 0x3F80). PV-MFMA col 8 then accumulates
  // l[n] = sum_m P[n][m] for free. Rows 9-15 stay garbage (discarded lanes).
  {
    uint* vo = (uint*)(ws + OFF_VTB);
    for (int i = gid; i < 32768; i += gsz) {
      int head = i >> 9, mw = i & 511;
      vo[head * 8192 + 4096 + mw] = 0x3F803F80u;
    }
  }

  // halo zeroing: xpb (16 uint4/px), apb (8 uint4/px)
  {
    uint4 z = {0u, 0u, 0u, 0u};
    uint4* xp = (uint4*)(ws + OFF_XPB);
    uint4* ap = (uint4*)(ws + OFF_APB);
    for (int s = gid; s < 9248; s += gsz) {
      int pb = s / 1156, rem = s - pb * 1156;
      int y = rem / 34, x = rem - y * 34;
      if (y == 0 || y == 33 || x == 0 || x == 33) {
        uint4* d1 = xp + (size_t)s * 16;
#pragma unroll
        for (int k = 0; k < 16; k++) d1[k] = z;
        uint4* d2 = ap + (size_t)s * 8;
#pragma unroll
        for (int k = 0; k < 8; k++) d2[k] = z;
      }
    }
  }

  // w_general -> wgb bf16 [kykx][co][ci]
  {
    ushort* wgb = (ushort*)(ws + OFF_WGB);
    for (int s = gid; s < 73728; s += gsz) {
      int kykx = s >> 13, co = (s >> 7) & 63, ci = s & 127;
      int si = (co * 128 + ci) * 9 + kykx;
      wgb[s] = f32 ? f2b(((const float*)p1)[si]) : ((const ushort*)p1)[si];
    }
  }
  // w_out -> wob bf16 [kykx][co][ci]
  {
    ushort* wob = (ushort*)(ws + OFF_WOB);
    for (int s = gid; s < 36864; s += gsz) {
      int kykx = s >> 12, co = (s >> 6) & 63, ci = s & 63;
      int si = (co * 64 + ci) * 9 + kykx;
      wob[s] = f32 ? f2b(((const float*)p5)[si]) : ((const ushort*)p5)[si];
    }
  }
  // w_qkv -> wqb bf16 [co][ci] (already [192][128] contiguous)
  {
    ushort* wqb = (ushort*)(ws + OFF_WQB);
    for (int s = gid; s < 24576; s += gsz) {
      wqb[s] = f32 ? f2b(((const float*)p3)[s]) : ((const ushort*)p3)[s];
    }
  }

  // x -> xpb interior transpose (blocks 0..127): 64 px x 128 ci per block
  if (blockIdx.x < 128) {
    int w = t >> 6, lane = t & 63;
    int b = blockIdx.x >> 4;
    int pp0 = (blockIdx.x & 15) * 64;
    if (f32) {
      const float* xs = (const float*)p0 + (size_t)b * 131072 + pp0;
#pragma unroll 4
      for (int i = 0; i < 16; i++) {
        int cp = w * 16 + i;
        float v0 = xs[(size_t)(2 * cp) * 1024 + lane];
        float v1 = xs[(size_t)(2 * cp + 1) * 1024 + lane];
        lds[cp][lane] = (uint)f2b(v0) | ((uint)f2b(v1) << 16);
      }
    } else {
      const ushort* xs = (const ushort*)p0 + (size_t)b * 131072 + pp0;
#pragma unroll 4
      for (int i = 0; i < 16; i++) {
        int cp = w * 16 + i;
        uint v0 = xs[(size_t)(2 * cp) * 1024 + lane];
        uint v1 = xs[(size_t)(2 * cp + 1) * 1024 + lane];
        lds[cp][lane] = v0 | (v1 << 16);
      }
    }
    __syncthreads();
    uint* xp32 = (uint*)(ws + OFF_XPB);
#pragma unroll 4
    for (int i = 0; i < 16; i++) {
      int p = w * 16 + i;
      int pp = pp0 + p;
      int y = pp >> 5, x = pp & 31;
      xp32[((size_t)(b * 34 + y + 1) * 34 + x + 1) * 64 + lane] = lds[lane][p];
    }
  }
}

// ---------------------------------------------------------------------------
// Kernel 1: qkv 1x1 conv as bf16 MFMA implicit GEMM on xpb center taps.
// grid (pxtile=64, b=8) = 512 blocks, 4 waves. Wave w covers co-groups
// {w, w+4, w+8} (q co 0..63, k co 64..127, v co 128..191).
// ---------------------------------------------------------------------------
__global__ __launch_bounds__(256) void qkv_mfma_kernel(
    const ushort* __restrict__ xp, const ushort* __restrict__ wqb,
    const float* __restrict__ bias, float* __restrict__ qbuf,
    ushort* __restrict__ kb16, ushort* __restrict__ vtb)
{
  int pt = blockIdx.x;            // px tile: 16 px
  int b  = blockIdx.y;
  int lane = threadIdx.x & 63;
  int w = threadIdx.x >> 6;       // wave 0..3
  int n = lane & 15;              // shared m/n index
  int kg = lane >> 4;             // k-group (8 ci each)
  int p0 = pt * 16;
  int px = p0 + n;
  int y = px >> 5, x = px & 31;

  const ushort* bbase = xp + ((size_t)(b * 34 + y + 1) * 34 + (x + 1)) * 128 + kg * 8;
  bf16x8 Bf[4];
#pragma unroll
  for (int c = 0; c < 4; c++) Bf[c] = *(const bf16x8*)(bbase + c * 32);

  f32x4 acc0 = {0.f, 0.f, 0.f, 0.f};
  f32x4 acc1 = {0.f, 0.f, 0.f, 0.f};
  f32x4 acc2 = {0.f, 0.f, 0.f, 0.f};
  {
    const ushort* abase = wqb + (size_t)(w * 16 + n) * 128 + kg * 8;
#pragma unroll
    for (int c = 0; c < 4; c++) {
      bf16x8 A = *(const bf16x8*)(abase + c * 32);
      acc0 = __builtin_amdgcn_mfma_f32_16x16x32_bf16(A, Bf[c], acc0, 0, 0, 0);
    }
  }
  {
    const ushort* abase = wqb + (size_t)((w + 4) * 16 + n) * 128 + kg * 8;
#pragma unroll
    for (int c = 0; c < 4; c++) {
      bf16x8 A = *(const bf16x8*)(abase + c * 32);
      acc1 = __builtin_amdgcn_mfma_f32_16x16x32_bf16(A, Bf[c], acc1, 0, 0, 0);
    }
  }
  {
    const ushort* abase = wqb + (size_t)((w + 8) * 16 + n) * 128 + kg * 8;
#pragma unroll
    for (int c = 0; c < 4; c++) {
      bf16x8 A = *(const bf16x8*)(abase + c * 32);
      acc2 = __builtin_amdgcn_mfma_f32_16x16x32_bf16(A, Bf[c], acc2, 0, 0, 0);
    }
  }

  // epilogue: D row = kg*4+r (co within group), D col = n (px)
#pragma unroll
  for (int r = 0; r < 4; r++) {
    int co = w * 16 + kg * 4 + r;             // 0..63
    float v = acc0[r] + bias[co];
    qbuf[((size_t)b * 64 + co) * NP + px] = v * QSCALE;
  }
#pragma unroll
  for (int r = 0; r < 4; r++) {
    int co = (w + 4) * 16 + kg * 4 + r;       // 64..127
    float v = acc1[r] + bias[co];
    kb16[((size_t)b * 64 + (co - 64)) * NP + px] = f2b(v);
  }
#pragma unroll
  for (int r = 0; r < 4; r++) {
    int co = (w + 8) * 16 + kg * 4 + r;       // 128..191
    float v = acc2[r] + bias[co];
    int ch = co - 128;
    int h = ch >> 3;
    int d0 = px & 7;                          // 0..7: never touches ones row 8
    int m  = (ch & 7) * 128 + (px >> 3);
    vtb[((size_t)(b * 8 + h) * 16 + d0) * 1024 + m] = f2b(v);
  }
}

// ---------------------------------------------------------------------------
// conv3x3 body as bf16 MFMA implicit GEMM; dual acc chains.
// ---------------------------------------------------------------------------
template <int CINT>
__device__ __forceinline__ void conv_body(
    const ushort* __restrict__ xp, const ushort* __restrict__ wp,
    const float* __restrict__ bias, void* __restrict__ out,
    int co_base, const int* __restrict__ flag, int pt, int b)
{
  int lane = threadIdx.x & 63;
  int w = threadIdx.x >> 6;       // wave -> co group (16 co)
  int n = lane & 15;              // A: m (co); B: n (px); shared index
  int kg = lane >> 4;             // k-group (8 ci each)
  int p0 = pt * 16;
  int y = p0 >> 5, x0 = p0 & 31;

  const ushort* abase = wp + (size_t)(w * 16 + n) * CINT + kg * 8;
  const ushort* bbase = xp + ((size_t)(b * 34 + y) * 34 + x0 + n) * CINT + kg * 8;

  f32x4 acc0 = {0.f, 0.f, 0.f, 0.f};
  f32x4 acc1 = {0.f, 0.f, 0.f, 0.f};
#pragma unroll
  for (int c = 0; c < CINT / 32; c++) {
    int ci0 = c * 32;
#pragma unroll
    for (int kp = 0; kp < 9; kp++) {
      int ky = kp / 3, kx = kp - ky * 3;
      bf16x8 A = *(const bf16x8*)(abase + (size_t)kp * 64 * CINT + ci0);
      bf16x8 B = *(const bf16x8*)(bbase + (size_t)(ky * 34 + kx) * CINT + ci0);
      if (kp & 1) acc1 = __builtin_amdgcn_mfma_f32_16x16x32_bf16(A, B, acc1, 0, 0, 0);
      else        acc0 = __builtin_amdgcn_mfma_f32_16x16x32_bf16(A, B, acc0, 0, 0, 0);
    }
  }

  int f32o = *flag;
#pragma unroll
  for (int r = 0; r < 4; r++) {
    int co = w * 16 + kg * 4 + r;        // D row = (lane>>4)*4 + r
    float v = acc0[r] + acc1[r] + bias[co];
    size_t eoff = ((size_t)b * 128 + co_base + co) * 1024 + p0 + n;   // D col = n
    if (f32o) ((float*)out)[eoff] = v;
    else ((bf16*)out)[eoff] = __float2bfloat16(v);
  }
}

// ---------------------------------------------------------------------------
// Kernel 2: MERGED: blocks 0..1023 = MFMA flash attention; blocks 1024..1535 =
// conv3x3 co 0..63. LDS 25.6KB -> 6 blocks/CU -> all 1536 blocks co-resident.
// Attention m-loop per 32-chunk: 2 S-MFMAs (16x16x32, d=8 in quad0 of K) ->
// exp chain -> P->LDS round-trip (C-layout -> A-layout) -> 1 PV-MFMA whose
// col 8 (V^T ones row) accumulates l for free.
// ---------------------------------------------------------------------------
__global__ __launch_bounds__(256, 4) void attn_conv_kernel(
    const float* __restrict__ qbuf, const ushort* __restrict__ kb16, const ushort* __restrict__ vtb,
    const float* __restrict__ krh, const float* __restrict__ krw,
    ushort* __restrict__ apb,
    const ushort* __restrict__ xp, const ushort* __restrict__ wgb,
    const float* __restrict__ bg, void* __restrict__ out, const int* __restrict__ flag)
{
  int bx = blockIdx.x;
  if (bx >= 1024) {
    int id = bx - 1024;
    conv_body<128>(xp, wgb, bg, out, 0, flag, id & 63, id >> 6);
    return;
  }

  __shared__ float bw2[2][NP];        // 8 KB (scaled by log2e)
  __shared__ float bhT[2][32][32];    // 8 KB (scaled by log2e)
  // qsT (prologue-only, 2KB) and Plds (main-loop-only, 5KB) share storage;
  // the __syncthreads after the atomicMax round separates their lifetimes.
  __shared__ __align__(16) char qpun[5120];
  __shared__ float krhs[64][8];       // 2 KB
  __shared__ float krws[64][8];       // 2 KB
  __shared__ int smax[3];
  float (*qsT)[32][8]   = (float (*)[32][8])qpun;    // [2][32][8]
  ushort (*Plds)[16][40] = (ushort (*)[16][40])qpun; // [4][16][40]

  int t = threadIdx.x;
  int cp = bx & 15, h = (bx >> 4) & 7, b = bx >> 7;
  int C0 = cp * 2;
  const float* qbase = qbuf + ((size_t)b * 64 + h * 8) * NP;
  const uint4* kb4 = (const uint4*)(kb16 + ((size_t)b * 64 + h * 8) * NP);
  const ushort* vth = vtb + (size_t)(b * 8 + h) * 16384;

  if (t < 3) smax[t] = (t == 0) ? 0 : fenc(-3.0e38f);

  for (int idx = t; idx < 63 * 8; idx += 256) {
    krhs[idx >> 3][idx & 7] = krh[idx];
    krws[idx >> 3][idx & 7] = krw[idx];
  }
  {
    int d = t >> 5, r = t & 31;      // 256 threads cover [8][32]
    float2 qv = *(const float2*)(qbase + (size_t)d * NP + r * 32 + C0);
    qsT[0][r][d] = qv.x;
    qsT[1][r][d] = qv.y;
  }
  // scan bf16 flat_k rows for max ||k_m||^2 (same data the MFMA consumes)
  float kn2 = 0.f;
#pragma unroll
  for (int rr = 0; rr < 4; rr++) {
    uint4 ku = kb4[rr * 256 + t];
    f32x2 k0 = up2(ku.x), k1 = up2(ku.y), k2 = up2(ku.z), k3 = up2(ku.w);
    f32x2 s2 = k0 * k0;
    s2 = __builtin_elementwise_fma(k1, k1, s2);
    s2 = __builtin_elementwise_fma(k2, k2, s2);
    s2 = __builtin_elementwise_fma(k3, k3, s2);
    kn2 = fmaxf(kn2, s2[0] + s2[1]);
  }
  __syncthreads();
  atomicMax(&smax[0], __float_as_int(kn2));

  float bwm = -3.0e38f;
  for (int idx = t; idx < 2048; idx += 256) {
    int cs = idx >> 10, m = idx & 1023;
    int rg = m >> 5, j2 = m & 31;
    float s = dot8(qsT[cs][rg], krws[j2 - rg + 31]) * LOG2E;
    bw2[cs][m] = s;
    bwm = fmaxf(bwm, s);
  }
  float bhm = -3.0e38f;
  for (int idx = t; idx < 2048; idx += 256) {
    int cs = idx >> 10, r = idx & 1023;
    int i = r >> 5, J = r & 31;
    float s = dot8(qsT[cs][i], krhs[J - (C0 + cs) + 31]) * LOG2E;
    bhT[cs][i][J] = s;
    bhm = fmaxf(bhm, s);
  }
  atomicMax(&smax[1], fenc(bwm));
  atomicMax(&smax[2], fenc(bhm));
  __syncthreads();     // also ends qsT lifetime; Plds may now reuse qpun

  float kmaxn = sqrtf(__int_as_float(smax[0]));
  float bmax = fdec(smax[1]) + fdec(smax[2]);

  int w = t >> 6, lane = t & 63;
  int quad = lane >> 4, nIdx = lane & 15;
  int n0 = cp * 64 + w * 16;
  int nQ = n0 + nIdx;
  int Cs = w >> 1;
  int J = ((w & 1) << 4) + nIdx;       // n & 31 for this lane's column

  const bf16x8 zero8 = {0, 0, 0, 0, 0, 0, 0, 0};

  // Q B-frag (bf16): quad 0 holds the 8 real d values, others zero.
  // Mn = ||q~|| * kmax + bmax using the bf16-rounded q (exact upper bound).
  const float* qrow = qbase + (size_t)nQ * 8;
  bf16x8 Bq = zero8;
  float nn = 0.f;
  ushort ub[8];
#pragma unroll
  for (int d = 0; d < 8; d++) {
    float v = qrow[d] * LOG2E;
    ub[d] = f2b(v);
    float vr = __uint_as_float((uint)ub[d] << 16);
    nn = fmaf(vr, vr, nn);
  }
  if (quad == 0) {
#pragma unroll
    for (int d = 0; d < 8; d++) Bq[d] = (short)ub[d];
  }
  float Mn = sqrtf(nn) * kmaxn + bmax;

  f32x4 accO = {0.f, 0.f, 0.f, 0.f};
  ushort* prow = &Plds[w][nIdx][0];

#pragma unroll 2
  for (int mc = 0; mc < 32; ++mc) {
    int mb = mc * 32;
    float pre = bhT[Cs][mc][J] - Mn;
    ushort pb[8];
#pragma unroll
    for (int s = 0; s < 2; ++s) {
      int mt = mb + s * 16;
      bf16x8 Ak = *(const bf16x8*)(kb4 + mt + nIdx);   // 16B = flat_k row
      f32x4 S = __builtin_amdgcn_mfma_f32_16x16x32_bf16(Ak, Bq, f32x4{0.f,0.f,0.f,0.f}, 0, 0, 0);
      float4 bw4 = *(const float4*)&bw2[Cs][mt + (quad << 2)];
      const float bwv[4] = {bw4.x, bw4.y, bw4.z, bw4.w};
#pragma unroll
      for (int r = 0; r < 4; ++r) {
        float p = EXP2F(S[r] + bwv[r] + pre);
        pb[s * 4 + r] = f2b(p);
      }
    }
    // P -> LDS (C-layout rows m=quad*4+r per tile), then read back A-layout
    uint2 w0, w1;
    w0.x = (uint)pb[0] | ((uint)pb[1] << 16);
    w0.y = (uint)pb[2] | ((uint)pb[3] << 16);
    w1.x = (uint)pb[4] | ((uint)pb[5] << 16);
    w1.y = (uint)pb[6] | ((uint)pb[7] << 16);
    *(uint2*)(prow + (quad << 2))        = w0;
    *(uint2*)(prow + 16 + (quad << 2))   = w1;
    // same-wave LDS: compiler orders via lgkmcnt; no barrier needed
    bf16x8 Ap = *(const bf16x8*)(prow + (quad << 3));
    bf16x8 Bv = *(const bf16x8*)(vth + (size_t)nIdx * 1024 + mb + (quad << 3));
    accO = __builtin_amdgcn_mfma_f32_16x16x32_bf16(Ap, Bv, accO, 0, 0, 0);
  }

  // l[n=4q+r] sits in lane (quad*16 + 8)'s accO[r] (V^T ones row -> col 8)
  int srcl = (lane & 48) | 8;
  float lr[4];
#pragma unroll
  for (int r = 0; r < 4; ++r) lr[r] = __shfl(accO[r], srcl);

  // O: lane holds O[n = n0+quad*4+r][d = nIdx] (d >= 8 lanes discard)
  if (nIdx < 8) {
#pragma unroll
    for (int r = 0; r < 4; ++r) {
      int n = n0 + (quad << 2) + r;
      float v = accO[r] / lr[r];
      apb[((size_t)(b * 34 + (n >> 5) + 1) * 34 + (n & 31) + 1) * 64 + h * 8 + nIdx] = f2b(v);
    }
  }
}

// ---------------------------------------------------------------------------
// Kernel 3: standalone conv3x3 (co 64..127, reads apb).
// ---------------------------------------------------------------------------
template <int CINT>
__global__ __launch_bounds__(256) void conv_mfma_kernel(
    const ushort* __restrict__ xp, const ushort* __restrict__ wp,
    const float* __restrict__ bias, void* __restrict__ out,
    int co_base, const int* __restrict__ flag)
{
  conv_body<CINT>(xp, wp, bias, out, co_base, flag, blockIdx.x, blockIdx.y);
}

// ---------------------------------------------------------------------------
extern "C" void kernel_launch(void* const* d_in, const int* in_sizes, int n_in,
                              void* d_out, int out_size, void* d_ws, size_t ws_size,
                              hipStream_t stream) {
  float* ws = (float*)d_ws;
  float*  qbuf  = ws + OFF_QBUF;
  ushort* kb16  = (ushort*)(ws + OFF_KB16);
  ushort* vtb   = (ushort*)(ws + OFF_VTB);
  ushort* xpb   = (ushort*)(ws + OFF_XPB);
  ushort* apb   = (ushort*)(ws + OFF_APB);
  ushort* wgb   = (ushort*)(ws + OFF_WGB);
  ushort* wob   = (ushort*)(ws + OFF_WOB);
  ushort* wqb   = (ushort*)(ws + OFF_WQB);
  float*  bgf   = ws + OFF_BG;
  float*  bqkvf = ws + OFF_BQKV;
  float*  bof   = ws + OFF_BO;
  float*  krhf  = ws + OFF_KRH;
  float*  krwf  = ws + OFF_KRW;
  int*    flag  = (int*)(ws + OFF_FLAG);

  cvt_kernel<<<512, 256, 0, stream>>>(d_in[0], d_in[1], d_in[2], d_in[3], d_in[4],
                                      d_in[5], d_in[6], d_in[7], d_in[8], ws, flag);
  qkv_mfma_kernel<<<dim3(64, 8), 256, 0, stream>>>(xpb, wqb, bqkvf, qbuf, kb16, vtb);
  attn_conv_kernel<<<1536, 256, 0, stream>>>(qbuf, kb16, vtb, krhf, krwf, apb,
                                             xpb, wgb, bgf, d_out, flag);
  conv_mfma_kernel<64><<<dim3(64, 8), 256, 0, stream>>>(apb, wob, bof, d_out, 64, flag);
}

// Round 4
// 140.980 us; speedup vs baseline: 1.1536x; 1.0616x over previous
//
#include <hip/hip_runtime.h>
#include <hip/hip_bf16.h>

// AAConv2d: B=8, CIN=128, H=W=32, COUT=128, K=3, DK=DV=64, NH=8, dkh=dvh=8
// out[:, 0:64]  = conv3x3(x, w_general) + b_general
// out[:, 64:128]= conv3x3(attn_combined, w_out) + b_out
// Rel logits (verified): logits[n,m] += dot(q[:, m>>5, n>>5], krw[(m&31)-(m>>5)+31])
//                                    + dot(q[:, m>>5, n>>5], krh[(n&31)-(n>>5)+31])
// flat_q/flat_k/flat_v are RAW reshapes: row n = linear elements n*8..n*8+7 of
// the channel-major (8,1024) head block.
// R17: REVERT to the best-measured R14 configuration (attn 49.3us, total
// 142.7us): vtb fully zeroed in cvt, Ak quad-cndmask, lpart+lred l-reduction,
// padded krhs/krws[64][12], separate qsT/Plds, LDS 30208 (5 blocks/CU).
// R15 (K=16 PV) and R16 (LDS diet + ones-row bundle) both regressed; their
// deltas are reverted wholesale. Single new change: s_setprio(1) for the
// attention role only — attn waves are the latency-critical long pole and
// share CUs with fast conv waves, the exact regime where setprio pays
// (learn_hip m191: +4-7% attn).

#define NP 1024
#define QSCALE 2.8284271247461903f   // q / (8^-0.5) = q*sqrt(8)
#define LOG2E  1.4426950408889634f

using bf16 = __hip_bfloat16;
typedef unsigned short ushort;
typedef unsigned int uint;
using bf16x8 = __attribute__((ext_vector_type(8))) short;  // 8 bf16 = 4 VGPRs
using f32x4  = __attribute__((ext_vector_type(4))) float;
using f32x2  = __attribute__((ext_vector_type(2))) float;

__device__ __forceinline__ float b2f(bf16 v) { return __bfloat162float(v); }
__device__ __forceinline__ ushort f2b(float v) {
  bf16 h = __float2bfloat16(v);
  ushort u; __builtin_memcpy(&u, &h, 2); return u;
}
__device__ __forceinline__ f32x2 up2(uint u) {   // 2 packed bf16 -> 2 f32
  f32x2 r;
  r[0] = __uint_as_float(u << 16);
  r[1] = __uint_as_float(u & 0xffff0000u);
  return r;
}

__device__ __forceinline__ float dot8(const float* a, const float* b) {
  float s = a[0] * b[0];
  s = fmaf(a[1], b[1], s); s = fmaf(a[2], b[2], s); s = fmaf(a[3], b[3], s);
  s = fmaf(a[4], b[4], s); s = fmaf(a[5], b[5], s); s = fmaf(a[6], b[6], s);
  s = fmaf(a[7], b[7], s);
  return s;
}

__device__ __forceinline__ int fenc(float f) { int i = __float_as_int(f); return i < 0 ? (i ^ 0x7fffffff) : i; }
__device__ __forceinline__ float fdec(int i) { return __int_as_float(i < 0 ? (i ^ 0x7fffffff) : i); }

#if defined(__has_builtin)
#if __has_builtin(__builtin_amdgcn_exp2f)
#define EXP2F __builtin_amdgcn_exp2f
#else
#define EXP2F exp2f
#endif
#else
#define EXP2F exp2f
#endif

#if defined(__has_builtin)
#if __has_builtin(__builtin_amdgcn_s_setprio)
#define SETPRIO(n) __builtin_amdgcn_s_setprio(n)
#else
#define SETPRIO(n) asm volatile("s_setprio " #n)
#endif
#else
#define SETPRIO(n) asm volatile("s_setprio " #n)
#endif

// ---- workspace float offsets ----------------------------------------------
#define OFF_QBUF   0          // f32 [8][64][1024]
#define OFF_KB16   524288     // ushort[8][64][1024] raw channel-major bf16
#define OFF_VTB    786432     // ushort[64 heads][16][1024] V^T (rows 8-15 zero)
#define OFF_XPB    1310720    // ushort[8][34][34][128]
#define OFF_APB    1902592    // ushort[8][34][34][64]
#define OFF_WGB    2198528    // ushort[9][64][128]
#define OFF_WOB    2235392    // ushort[9][64][64]
#define OFF_BG     2253824
#define OFF_BQKV   2253888
#define OFF_BO     2254080
#define OFF_KRH    2254144
#define OFF_KRW    2254648
#define OFF_FLAG   2255152
#define OFF_WQB    2255168    // ushort[192][128] bf16 w_qkv (16B-aligned)

// ---------------------------------------------------------------------------
// Kernel 0: dtype detect + small fp32 copies + halo zeroing + vtb zeroing +
// weight bf16 transforms (wgb, wob, wqb) + (blocks<128) x->xpb bf16 transpose.
// ---------------------------------------------------------------------------
__global__ __launch_bounds__(256) void cvt_kernel(
    const void* __restrict__ p0, const void* __restrict__ p1, const void* __restrict__ p2,
    const void* __restrict__ p3, const void* __restrict__ p4, const void* __restrict__ p5,
    const void* __restrict__ p6, const void* __restrict__ p7, const void* __restrict__ p8,
    float* __restrict__ ws, int* __restrict__ flag)
{
  __shared__ int partial[4];
  __shared__ uint lds[64][65];
  int t = threadIdx.x;
  const unsigned* xraw = (const unsigned*)p0;
  int cnt = 0;
  for (int i = t; i < 1024; i += 256) {
    unsigned elo = (xraw[i] >> 7) & 0xffu;
    cnt += (elo >= 64u && elo <= 133u) ? 1 : 0;
  }
#pragma unroll
  for (int off = 1; off < 64; off <<= 1) cnt += __shfl_xor(cnt, off);
  if ((t & 63) == 0) partial[t >> 6] = cnt;
  __syncthreads();
  int tot = partial[0] + partial[1] + partial[2] + partial[3];
  int f32 = (tot >= 650) ? 0 : 1;   // 1 = fp32 tensors, 0 = bf16 tensors
  if (blockIdx.x == 0 && t == 0) *flag = f32;

  int gsz = gridDim.x * 256;
  int gid = blockIdx.x * 256 + t;

  // small fp32 copies (bg, bqkv, bo, krh, krw)
  const void* src[5] = {p2, p4, p6, p7, p8};
  const int   n[5]    = {64, 192, 64, 504, 504};
  const int   doff[5] = {OFF_BG, OFF_BQKV, OFF_BO, OFF_KRH, OFF_KRW};
#pragma unroll
  for (int s = 0; s < 5; s++) {
    float* dst = ws + doff[s];
    if (f32) { const float* sp = (const float*)src[s];
      for (int i = gid; i < n[s]; i += gsz) dst[i] = sp[i];
    } else { const bf16* sp = (const bf16*)src[s];
      for (int i = gid; i < n[s]; i += gsz) dst[i] = b2f(sp[i]);
    }
  }

  // zero entire vtb (qkv fills rows 0-7 later; rows 8-15 stay zero)
  {
    float4* z = (float4*)(ws + OFF_VTB);
    for (int i = gid; i < 131072; i += gsz) z[i] = float4{0.f, 0.f, 0.f, 0.f};
  }

  // halo zeroing: xpb (16 uint4/px), apb (8 uint4/px)
  {
    uint4 z = {0u, 0u, 0u, 0u};
    uint4* xp = (uint4*)(ws + OFF_XPB);
    uint4* ap = (uint4*)(ws + OFF_APB);
    for (int s = gid; s < 9248; s += gsz) {
      int pb = s / 1156, rem = s - pb * 1156;
      int y = rem / 34, x = rem - y * 34;
      if (y == 0 || y == 33 || x == 0 || x == 33) {
        uint4* d1 = xp + (size_t)s * 16;
#pragma unroll
        for (int k = 0; k < 16; k++) d1[k] = z;
        uint4* d2 = ap + (size_t)s * 8;
#pragma unroll
        for (int k = 0; k < 8; k++) d2[k] = z;
      }
    }
  }

  // w_general -> wgb bf16 [kykx][co][ci]
  {
    ushort* wgb = (ushort*)(ws + OFF_WGB);
    for (int s = gid; s < 73728; s += gsz) {
      int kykx = s >> 13, co = (s >> 7) & 63, ci = s & 127;
      int si = (co * 128 + ci) * 9 + kykx;
      wgb[s] = f32 ? f2b(((const float*)p1)[si]) : ((const ushort*)p1)[si];
    }
  }
  // w_out -> wob bf16 [kykx][co][ci]
  {
    ushort* wob = (ushort*)(ws + OFF_WOB);
    for (int s = gid; s < 36864; s += gsz) {
      int kykx = s >> 12, co = (s >> 6) & 63, ci = s & 63;
      int si = (co * 64 + ci) * 9 + kykx;
      wob[s] = f32 ? f2b(((const float*)p5)[si]) : ((const ushort*)p5)[si];
    }
  }
  // w_qkv -> wqb bf16 [co][ci] (already [192][128] contiguous)
  {
    ushort* wqb = (ushort*)(ws + OFF_WQB);
    for (int s = gid; s < 24576; s += gsz) {
      wqb[s] = f32 ? f2b(((const float*)p3)[s]) : ((const ushort*)p3)[s];
    }
  }

  // x -> xpb interior transpose (blocks 0..127): 64 px x 128 ci per block
  if (blockIdx.x < 128) {
    int w = t >> 6, lane = t & 63;
    int b = blockIdx.x >> 4;
    int pp0 = (blockIdx.x & 15) * 64;
    if (f32) {
      const float* xs = (const float*)p0 + (size_t)b * 131072 + pp0;
#pragma unroll 4
      for (int i = 0; i < 16; i++) {
        int cp = w * 16 + i;
        float v0 = xs[(size_t)(2 * cp) * 1024 + lane];
        float v1 = xs[(size_t)(2 * cp + 1) * 1024 + lane];
        lds[cp][lane] = (uint)f2b(v0) | ((uint)f2b(v1) << 16);
      }
    } else {
      const ushort* xs = (const ushort*)p0 + (size_t)b * 131072 + pp0;
#pragma unroll 4
      for (int i = 0; i < 16; i++) {
        int cp = w * 16 + i;
        uint v0 = xs[(size_t)(2 * cp) * 1024 + lane];
        uint v1 = xs[(size_t)(2 * cp + 1) * 1024 + lane];
        lds[cp][lane] = v0 | (v1 << 16);
      }
    }
    __syncthreads();
    uint* xp32 = (uint*)(ws + OFF_XPB);
#pragma unroll 4
    for (int i = 0; i < 16; i++) {
      int p = w * 16 + i;
      int pp = pp0 + p;
      int y = pp >> 5, x = pp & 31;
      xp32[((size_t)(b * 34 + y + 1) * 34 + x + 1) * 64 + lane] = lds[lane][p];
    }
  }
}

// ---------------------------------------------------------------------------
// Kernel 1: qkv 1x1 conv as bf16 MFMA implicit GEMM on xpb center taps.
// grid (pxtile=64, b=8) = 512 blocks, 4 waves. Wave w covers co-groups
// {w, w+4, w+8} (q co 0..63, k co 64..127, v co 128..191).
// ---------------------------------------------------------------------------
__global__ __launch_bounds__(256) void qkv_mfma_kernel(
    const ushort* __restrict__ xp, const ushort* __restrict__ wqb,
    const float* __restrict__ bias, float* __restrict__ qbuf,
    ushort* __restrict__ kb16, ushort* __restrict__ vtb)
{
  int pt = blockIdx.x;            // px tile: 16 px
  int b  = blockIdx.y;
  int lane = threadIdx.x & 63;
  int w = threadIdx.x >> 6;       // wave 0..3
  int n = lane & 15;              // shared m/n index
  int kg = lane >> 4;             // k-group (8 ci each)
  int p0 = pt * 16;
  int px = p0 + n;
  int y = px >> 5, x = px & 31;

  const ushort* bbase = xp + ((size_t)(b * 34 + y + 1) * 34 + (x + 1)) * 128 + kg * 8;
  bf16x8 Bf[4];
#pragma unroll
  for (int c = 0; c < 4; c++) Bf[c] = *(const bf16x8*)(bbase + c * 32);

  f32x4 acc0 = {0.f, 0.f, 0.f, 0.f};
  f32x4 acc1 = {0.f, 0.f, 0.f, 0.f};
  f32x4 acc2 = {0.f, 0.f, 0.f, 0.f};
  {
    const ushort* abase = wqb + (size_t)(w * 16 + n) * 128 + kg * 8;
#pragma unroll
    for (int c = 0; c < 4; c++) {
      bf16x8 A = *(const bf16x8*)(abase + c * 32);
      acc0 = __builtin_amdgcn_mfma_f32_16x16x32_bf16(A, Bf[c], acc0, 0, 0, 0);
    }
  }
  {
    const ushort* abase = wqb + (size_t)((w + 4) * 16 + n) * 128 + kg * 8;
#pragma unroll
    for (int c = 0; c < 4; c++) {
      bf16x8 A = *(const bf16x8*)(abase + c * 32);
      acc1 = __builtin_amdgcn_mfma_f32_16x16x32_bf16(A, Bf[c], acc1, 0, 0, 0);
    }
  }
  {
    const ushort* abase = wqb + (size_t)((w + 8) * 16 + n) * 128 + kg * 8;
#pragma unroll
    for (int c = 0; c < 4; c++) {
      bf16x8 A = *(const bf16x8*)(abase + c * 32);
      acc2 = __builtin_amdgcn_mfma_f32_16x16x32_bf16(A, Bf[c], acc2, 0, 0, 0);
    }
  }

  // epilogue: D row = kg*4+r (co within group), D col = n (px)
#pragma unroll
  for (int r = 0; r < 4; r++) {
    int co = w * 16 + kg * 4 + r;             // 0..63
    float v = acc0[r] + bias[co];
    qbuf[((size_t)b * 64 + co) * NP + px] = v * QSCALE;
  }
#pragma unroll
  for (int r = 0; r < 4; r++) {
    int co = (w + 4) * 16 + kg * 4 + r;       // 64..127
    float v = acc1[r] + bias[co];
    kb16[((size_t)b * 64 + (co - 64)) * NP + px] = f2b(v);
  }
#pragma unroll
  for (int r = 0; r < 4; r++) {
    int co = (w + 8) * 16 + kg * 4 + r;       // 128..191
    float v = acc2[r] + bias[co];
    int ch = co - 128;
    int h = ch >> 3;
    int d0 = px & 7;
    int m  = (ch & 7) * 128 + (px >> 3);
    vtb[((size_t)(b * 8 + h) * 16 + d0) * 1024 + m] = f2b(v);
  }
}

// ---------------------------------------------------------------------------
// conv3x3 body as bf16 MFMA implicit GEMM; dual acc chains.
// ---------------------------------------------------------------------------
template <int CINT>
__device__ __forceinline__ void conv_body(
    const ushort* __restrict__ xp, const ushort* __restrict__ wp,
    const float* __restrict__ bias, void* __restrict__ out,
    int co_base, const int* __restrict__ flag, int pt, int b)
{
  int lane = threadIdx.x & 63;
  int w = threadIdx.x >> 6;       // wave -> co group (16 co)
  int n = lane & 15;              // A: m (co); B: n (px); shared index
  int kg = lane >> 4;             // k-group (8 ci each)
  int p0 = pt * 16;
  int y = p0 >> 5, x0 = p0 & 31;

  const ushort* abase = wp + (size_t)(w * 16 + n) * CINT + kg * 8;
  const ushort* bbase = xp + ((size_t)(b * 34 + y) * 34 + x0 + n) * CINT + kg * 8;

  f32x4 acc0 = {0.f, 0.f, 0.f, 0.f};
  f32x4 acc1 = {0.f, 0.f, 0.f, 0.f};
#pragma unroll
  for (int c = 0; c < CINT / 32; c++) {
    int ci0 = c * 32;
#pragma unroll
    for (int kp = 0; kp < 9; kp++) {
      int ky = kp / 3, kx = kp - ky * 3;
      bf16x8 A = *(const bf16x8*)(abase + (size_t)kp * 64 * CINT + ci0);
      bf16x8 B = *(const bf16x8*)(bbase + (size_t)(ky * 34 + kx) * CINT + ci0);
      if (kp & 1) acc1 = __builtin_amdgcn_mfma_f32_16x16x32_bf16(A, B, acc1, 0, 0, 0);
      else        acc0 = __builtin_amdgcn_mfma_f32_16x16x32_bf16(A, B, acc0, 0, 0, 0);
    }
  }

  int f32o = *flag;
#pragma unroll
  for (int r = 0; r < 4; r++) {
    int co = w * 16 + kg * 4 + r;        // D row = (lane>>4)*4 + r
    float v = acc0[r] + acc1[r] + bias[co];
    size_t eoff = ((size_t)b * 128 + co_base + co) * 1024 + p0 + n;   // D col = n
    if (f32o) ((float*)out)[eoff] = v;
    else ((bf16*)out)[eoff] = __float2bfloat16(v);
  }
}

// ---------------------------------------------------------------------------
// Kernel 2: MERGED: blocks 0..1023 = MFMA flash attention; blocks 1024..1535 =
// conv3x3 co 0..63 (independent; backfills CUs). Attention waves run at
// s_setprio(1): they are the latency-critical long pole sharing CUs with
// fast conv waves. Attention m-loop per 32-chunk: 2 S-MFMAs (16x16x32, d=8
// in quad0 of K) -> bias/exp2 -> P->LDS (bf16, padded rows) -> 1 PV-MFMA.
// ---------------------------------------------------------------------------
__global__ __launch_bounds__(256, 4) void attn_conv_kernel(
    const float* __restrict__ qbuf, const ushort* __restrict__ kb16, const ushort* __restrict__ vtb,
    const float* __restrict__ krh, const float* __restrict__ krw,
    ushort* __restrict__ apb,
    const ushort* __restrict__ xp, const ushort* __restrict__ wgb,
    const float* __restrict__ bg, void* __restrict__ out, const int* __restrict__ flag)
{
  int bx = blockIdx.x;
  if (bx >= 1024) {
    int id = bx - 1024;
    conv_body<128>(xp, wgb, bg, out, 0, flag, id & 63, id >> 6);
    return;
  }
  SETPRIO(1);

  __shared__ float bw2[2][NP];        // 8 KB (scaled by log2e)
  __shared__ float bhT[2][32][32];    // 8 KB (scaled by log2e)
  __shared__ float qsT[2][32][8];     // 2 KB
  __shared__ __align__(16) float krhs[64][12];  // 48B rows: 16B-aligned
  __shared__ __align__(16) float krws[64][12];
  __shared__ ushort Plds[4][16][40];  // 5 KB, row stride 40 (bank-safe)
  __shared__ float lred[4][16];
  __shared__ int smax[3];

  int t = threadIdx.x;
  int cp = bx & 15, h = (bx >> 4) & 7, b = bx >> 7;
  int C0 = cp * 2;
  const float* qbase = qbuf + ((size_t)b * 64 + h * 8) * NP;
  const uint4* kb4 = (const uint4*)(kb16 + ((size_t)b * 64 + h * 8) * NP);
  const ushort* vth = vtb + (size_t)(b * 8 + h) * 16384;

  if (t < 3) smax[t] = (t == 0) ? 0 : fenc(-3.0e38f);

  for (int idx = t; idx < 63 * 8; idx += 256) {
    krhs[idx >> 3][idx & 7] = krh[idx];
    krws[idx >> 3][idx & 7] = krw[idx];
  }
  for (int idx = t; idx < 512; idx += 256) {
    int cs = idx >> 8, d = (idx >> 5) & 7, r = idx & 31;
    qsT[cs][r][d] = qbase[(size_t)d * NP + r * 32 + (C0 + cs)];
  }
  // scan bf16 flat_k rows for max ||k_m||^2 (same data the MFMA consumes)
  float kn2 = 0.f;
#pragma unroll
  for (int rr = 0; rr < 4; rr++) {
    uint4 ku = kb4[rr * 256 + t];
    f32x2 k0 = up2(ku.x), k1 = up2(ku.y), k2 = up2(ku.z), k3 = up2(ku.w);
    f32x2 s2 = k0 * k0;
    s2 = __builtin_elementwise_fma(k1, k1, s2);
    s2 = __builtin_elementwise_fma(k2, k2, s2);
    s2 = __builtin_elementwise_fma(k3, k3, s2);
    kn2 = fmaxf(kn2, s2[0] + s2[1]);
  }
  __syncthreads();
  atomicMax(&smax[0], __float_as_int(kn2));

  float bwm = -3.0e38f;
  for (int idx = t; idx < 2048; idx += 256) {
    int cs = idx >> 10, m = idx & 1023;
    int rg = m >> 5, j2 = m & 31;
    float s = dot8(qsT[cs][rg], krws[j2 - rg + 31]) * LOG2E;
    bw2[cs][m] = s;
    bwm = fmaxf(bwm, s);
  }
  float bhm = -3.0e38f;
  for (int idx = t; idx < 2048; idx += 256) {
    int cs = idx >> 10, r = idx & 1023;
    int i = r >> 5, J = r & 31;
    float s = dot8(qsT[cs][i], krhs[J - (C0 + cs) + 31]) * LOG2E;
    bhT[cs][i][J] = s;
    bhm = fmaxf(bhm, s);
  }
  atomicMax(&smax[1], fenc(bwm));
  atomicMax(&smax[2], fenc(bhm));
  __syncthreads();

  float kmaxn = sqrtf(__int_as_float(smax[0]));
  float bmax = fdec(smax[1]) + fdec(smax[2]);

  int w = t >> 6, lane = t & 63;
  int quad = lane >> 4, nIdx = lane & 15;
  int n0 = cp * 64 + w * 16;
  int nQ = n0 + nIdx;
  int Cs = w >> 1;
  int J = ((w & 1) << 4) + nIdx;       // n & 31 for this lane's column

  const bf16x8 zero8 = {0, 0, 0, 0, 0, 0, 0, 0};

  // Q B-frag (bf16): quad 0 holds the 8 real d values, others zero.
  // Mn = ||q~|| * kmax + bmax using the bf16-rounded q (exact upper bound).
  const float* qrow = qbase + (size_t)nQ * 8;
  bf16x8 Bq = zero8;
  float nn = 0.f;
  ushort ub[8];
#pragma unroll
  for (int d = 0; d < 8; d++) {
    float v = qrow[d] * LOG2E;
    ub[d] = f2b(v);
    float vr = __uint_as_float((uint)ub[d] << 16);
    nn = fmaf(vr, vr, nn);
  }
  if (quad == 0) {
#pragma unroll
    for (int d = 0; d < 8; d++) Bq[d] = (short)ub[d];
  }
  float Mn = sqrtf(nn) * kmaxn + bmax;

  f32x4 accO = {0.f, 0.f, 0.f, 0.f};
  float lpart = 0.f;
  ushort* prow = &Plds[w][nIdx][0];

#pragma unroll 2
  for (int mc = 0; mc < 32; ++mc) {
    int mb = mc * 32;
    float pre = bhT[Cs][mc][J] - Mn;
    ushort pb[8];
#pragma unroll
    for (int s = 0; s < 2; ++s) {
      int mt = mb + s * 16;
      bf16x8 Ak = *(const bf16x8*)(kb4 + mt + nIdx);   // 16B = flat_k row
      if (quad != 0) Ak = zero8;
      f32x4 S = __builtin_amdgcn_mfma_f32_16x16x32_bf16(Ak, Bq, f32x4{0.f,0.f,0.f,0.f}, 0, 0, 0);
      float4 bw4 = *(const float4*)&bw2[Cs][mt + (quad << 2)];
      const float bwv[4] = {bw4.x, bw4.y, bw4.z, bw4.w};
#pragma unroll
      for (int r = 0; r < 4; ++r) {
        float p = EXP2F(S[r] + bwv[r] + pre);
        lpart += p;
        pb[s * 4 + r] = f2b(p);
      }
    }
    // P -> LDS (C-layout rows m=quad*4+r per tile), then read back A-layout
    uint2 w0, w1;
    w0.x = (uint)pb[0] | ((uint)pb[1] << 16);
    w0.y = (uint)pb[2] | ((uint)pb[3] << 16);
    w1.x = (uint)pb[4] | ((uint)pb[5] << 16);
    w1.y = (uint)pb[6] | ((uint)pb[7] << 16);
    *(uint2*)(prow + (quad << 2))        = w0;
    *(uint2*)(prow + 16 + (quad << 2))   = w1;
    // same-wave LDS: compiler orders via lgkmcnt; no barrier needed
    bf16x8 Ap = *(const bf16x8*)(prow + (quad << 3));
    bf16x8 Bv = *(const bf16x8*)(vth + (size_t)nIdx * 1024 + mb + (quad << 3));
    accO = __builtin_amdgcn_mfma_f32_16x16x32_bf16(Ap, Bv, accO, 0, 0, 0);
  }

  // l: lane has partial for col nIdx over its rows; reduce across quads
  lpart += __shfl_xor(lpart, 16);
  lpart += __shfl_xor(lpart, 32);
  if (lane < 16) lred[w][lane] = lpart;
  float4 lr4 = *(const float4*)&lred[w][quad << 2];
  const float lr[4] = {lr4.x, lr4.y, lr4.z, lr4.w};

  SETPRIO(0);
  // O: lane holds O[n = n0+quad*4+r][d = nIdx] (d >= 8 lanes discard)
  if (nIdx < 8) {
#pragma unroll
    for (int r = 0; r < 4; ++r) {
      int n = n0 + (quad << 2) + r;
      float v = accO[r] / lr[r];
      apb[((size_t)(b * 34 + (n >> 5) + 1) * 34 + (n & 31) + 1) * 64 + h * 8 + nIdx] = f2b(v);
    }
  }
}

// ---------------------------------------------------------------------------
// Kernel 3: standalone conv3x3 (co 64..127, reads apb).
// ---------------------------------------------------------------------------
template <int CINT>
__global__ __launch_bounds__(256) void conv_mfma_kernel(
    const ushort* __restrict__ xp, const ushort* __restrict__ wp,
    const float* __restrict__ bias, void* __restrict__ out,
    int co_base, const int* __restrict__ flag)
{
  conv_body<CINT>(xp, wp, bias, out, co_base, flag, blockIdx.x, blockIdx.y);
}

// ---------------------------------------------------------------------------
extern "C" void kernel_launch(void* const* d_in, const int* in_sizes, int n_in,
                              void* d_out, int out_size, void* d_ws, size_t ws_size,
                              hipStream_t stream) {
  float* ws = (float*)d_ws;
  float*  qbuf  = ws + OFF_QBUF;
  ushort* kb16  = (ushort*)(ws + OFF_KB16);
  ushort* vtb   = (ushort*)(ws + OFF_VTB);
  ushort* xpb   = (ushort*)(ws + OFF_XPB);
  ushort* apb   = (ushort*)(ws + OFF_APB);
  ushort* wgb   = (ushort*)(ws + OFF_WGB);
  ushort* wob   = (ushort*)(ws + OFF_WOB);
  ushort* wqb   = (ushort*)(ws + OFF_WQB);
  float*  bgf   = ws + OFF_BG;
  float*  bqkvf = ws + OFF_BQKV;
  float*  bof   = ws + OFF_BO;
  float*  krhf  = ws + OFF_KRH;
  float*  krwf  = ws + OFF_KRW;
  int*    flag  = (int*)(ws + OFF_FLAG);

  cvt_kernel<<<512, 256, 0, stream>>>(d_in[0], d_in[1], d_in[2], d_in[3], d_in[4],
                                      d_in[5], d_in[6], d_in[7], d_in[8], ws, flag);
  qkv_mfma_kernel<<<dim3(64, 8), 256, 0, stream>>>(xpb, wqb, bqkvf, qbuf, kb16, vtb);
  attn_conv_kernel<<<1536, 256, 0, stream>>>(qbuf, kb16, vtb, krhf, krwf, apb,
                                             xpb, wgb, bgf, d_out, flag);
  conv_mfma_kernel<64><<<dim3(64, 8), 256, 0, stream>>>(apb, wob, bof, d_out, 64, flag);
}